// Round 2
// baseline (419.525 us; speedup 1.0000x reference)
//
#include <hip/hip_runtime.h>

// Problem constants
#define DD   768      // appearance dim
#define NH   8        // heads
#define DKh  96       // key/geo dim

typedef __attribute__((ext_vector_type(8))) short short8;   // 8 bf16
typedef __attribute__((ext_vector_type(4))) float f32x4;

__device__ __forceinline__ unsigned short f2bf(float x) {
    union { float f; unsigned int u; } v; v.f = x;
    unsigned int r = v.u + 0x7FFFu + ((v.u >> 16) & 1u);   // RNE
    return (unsigned short)(r >> 16);
}

// ---------------- 1. f_a fp32 -> bf16 ----------------
__global__ __launch_bounds__(256) void k_cvt_a(const float* __restrict__ fa,
                                               unsigned short* __restrict__ abf) {
    int idx = blockIdx.x * 256 + threadIdx.x;          // 393216 float4 exactly
    float4 v = ((const float4*)fa)[idx];
    ushort4 o;
    o.x = f2bf(v.x); o.y = f2bf(v.y); o.z = f2bf(v.z); o.w = f2bf(v.w);
    ((ushort4*)abf)[idx] = o;
}

// ---------------- 2. W[K|Q|V] -> bf16, transposed to [col][d] ----------------
// input  WX_w: [8][768][96] fp32 ; output wbf[c*768+d], c = p*768 + h*96 + e
__global__ __launch_bounds__(256) void k_cvt_w(const float* __restrict__ wk,
                                               const float* __restrict__ wq,
                                               const float* __restrict__ wv,
                                               unsigned short* __restrict__ wbf) {
    __shared__ float ls[64 * 97];                      // pad 97: conflict-free
    int pid = blockIdx.x / 12;                         // 0..23 = (p,h)
    int db  = blockIdx.x % 12;                         // d-block of 64
    int p = pid >> 3, h = pid & 7;
    const float* src = (p == 0 ? wk : p == 1 ? wq : wv) + h * DD * DKh + db * 64 * DKh;
    int t = threadIdx.x;
#pragma unroll
    for (int i = 0; i < 24; ++i) {                     // 64 rows x 96, coalesced
        int f = t + 256 * i;
        int dl = f / 96, e = f - dl * 96;
        ls[dl * 97 + e] = src[f];
    }
    __syncthreads();
    unsigned short* dst = wbf + (p * 768 + h * 96) * DD + db * 64;
#pragma unroll
    for (int i = 0; i < 24; ++i) {
        int f = t + 256 * i;
        int e = f >> 6, dl = f & 63;
        dst[e * DD + dl] = f2bf(ls[dl * 97 + e]);
    }
}

// ---------------- 3. projections: C[2048x2304] = A x W, MFMA bf16 ----------------
// Block = 64 rows x 64 cols (waves take distinct 16-row strips; share B range via L1).
// outputs: kb[b,h,m,e] bf16 ; qb[b,h,n,e] bf16 (pre-scaled 1/sqrt(96)) ; vt[b,h,e,m] bf16
__global__ __launch_bounds__(256) void k_proj(const unsigned short* __restrict__ abf,
                                              const unsigned short* __restrict__ wbf,
                                              const float* __restrict__ wkb,
                                              const float* __restrict__ wqb,
                                              const float* __restrict__ wvb,
                                              unsigned short* __restrict__ kb,
                                              unsigned short* __restrict__ qb,
                                              unsigned short* __restrict__ vt) {
    int w = threadIdx.x >> 6, lane = threadIdx.x & 63;
    int lrow = lane & 15, quad = lane >> 4;
    int rt = blockIdx.x / 36, cg = blockIdx.x % 36;    // 32 row-tiles x 36 col-tiles
    int r0 = rt * 64 + w * 16;                         // wave: 16 rows x 64 cols
    int c0 = cg * 64;
    f32x4 z = {0.f, 0.f, 0.f, 0.f};
    f32x4 acc[4] = {z, z, z, z};
    for (int kk = 0; kk < DD; kk += 32) {
        short8 a = *(const short8*)(abf + (r0 + lrow) * DD + kk + quad * 8);
#pragma unroll
        for (int tt = 0; tt < 4; ++tt) {
            short8 b = *(const short8*)(wbf + (c0 + tt * 16 + lrow) * DD + kk + quad * 8);
            acc[tt] = __builtin_amdgcn_mfma_f32_16x16x32_bf16(a, b, acc[tt], 0, 0, 0);
        }
    }
    int rbase = r0 + quad * 4;
    int b_ = rbase >> 8, mbase = rbase & 255;
#pragma unroll
    for (int tt = 0; tt < 4; ++tt) {
        int cc = c0 + tt * 16 + lrow;                  // p uniform per tile; h may straddle
        int p = cc / 768, rm = cc - p * 768;
        int h = rm / 96,  e = rm - h * 96;
        float bias = (p == 0 ? wkb : p == 1 ? wqb : wvb)[h * 96 + e];
        if (p == 2) {                                  // V transposed: [e][m], m packed x4
            ushort4 v4;
            v4.x = f2bf(acc[tt][0] + bias);
            v4.y = f2bf(acc[tt][1] + bias);
            v4.z = f2bf(acc[tt][2] + bias);
            v4.w = f2bf(acc[tt][3] + bias);
            *(ushort4*)(vt + ((b_ * 8 + h) * 96 + e) * 256 + mbase) = v4;
        } else {
            float sc = (p == 1) ? 0.10206207261596577f : 1.0f;   // fold 1/sqrt(96) into Q
            unsigned short* dst = (p == 0 ? kb : qb) + ((b_ * 8 + h) * 256 + mbase) * 96 + e;
#pragma unroll
            for (int r = 0; r < 4; ++r)
                dst[r * 96] = f2bf((acc[tt][r] + bias) * sc);
        }
    }
}

// ---------------- 4. geometric bias: L[b,h,m,n] = log(max(pe.WG+b, 1e-6)) ----------------
// One thread per (b,m,n); lane reads its own contiguous 384B pe row via float4
// (full line consumption, 3/4 L1 hits). Weights are wave-uniform -> s_load.
// No LDS at all: HBM-bound (201 MB read floor).
__global__ __launch_bounds__(256) void k_wg(const float* __restrict__ pe,
                                            const float* __restrict__ wgw,
                                            const float* __restrict__ wgb,
                                            float* __restrict__ L) {
    int tid = blockIdx.x * 256 + threadIdx.x;          // 524288 = 8*256*256
    int n = tid & 255, m = (tid >> 8) & 255, b = tid >> 16;
    const float4* row = (const float4*)(pe + (size_t)tid * 96);
    float acc[8];
#pragma unroll
    for (int h = 0; h < 8; ++h) acc[h] = wgb[h];
#pragma unroll
    for (int g4 = 0; g4 < 24; ++g4) {
        float4 v = row[g4];
#pragma unroll
        for (int h = 0; h < 8; ++h) {
            acc[h] = fmaf(v.x, wgw[h * 96 + g4 * 4 + 0], acc[h]);
            acc[h] = fmaf(v.y, wgw[h * 96 + g4 * 4 + 1], acc[h]);
            acc[h] = fmaf(v.z, wgw[h * 96 + g4 * 4 + 2], acc[h]);
            acc[h] = fmaf(v.w, wgw[h * 96 + g4 * 4 + 3], acc[h]);
        }
    }
    int base = (b * 8 * 256 + m) * 256 + n;            // L[b,h,m,n], lanes n coalesced
#pragma unroll
    for (int h = 0; h < 8; ++h)
        L[base + h * 65536] = __logf(fmaxf(acc[h], 1e-6f));
}

// ---------------- 5. scores: L[m][n] += sum_e K[m,e] * Qscaled[n,e] ----------------
__global__ __launch_bounds__(256) void k_score(const unsigned short* __restrict__ kb,
                                               const unsigned short* __restrict__ qb,
                                               float* __restrict__ L) {
    int w = threadIdx.x >> 6, lane = threadIdx.x & 63;
    int lrow = lane & 15, quad = lane >> 4;
    int tid = blockIdx.x * 4 + w;
    int bh = tid >> 8, rem = tid & 255;
    int mt = rem >> 4, nt = rem & 15;
    int m0 = mt * 16, n0 = nt * 16;
    f32x4 acc = {0.f, 0.f, 0.f, 0.f};
    const unsigned short* ka = kb + (bh * 256 + m0 + lrow) * 96 + quad * 8;  // A rows=m
    const unsigned short* qa = qb + (bh * 256 + n0 + lrow) * 96 + quad * 8;  // B cols=n
#pragma unroll
    for (int kk = 0; kk < 96; kk += 32) {
        short8 a = *(const short8*)(ka + kk);
        short8 b = *(const short8*)(qa + kk);
        acc = __builtin_amdgcn_mfma_f32_16x16x32_bf16(a, b, acc, 0, 0, 0);
    }
    float* lp = L + (bh * 256 + m0 + quad * 4) * 256 + n0 + lrow;   // D[m][n] coalesced
#pragma unroll
    for (int r = 0; r < 4; ++r)
        lp[r * 256] += acc[r];
}

// ---------------- 6. softmax over m (per b,h,n) -> Pt[b,h,n,m] bf16, normalized ----------------
__global__ __launch_bounds__(256) void k_softmax(const float* __restrict__ L,
                                                 unsigned short* __restrict__ pt) {
    __shared__ float Ps[32 * 264];                     // 32 n-rows x 256 m, pad 264
    __shared__ float inv_s[32];
    int bh = blockIdx.x >> 3, nbk = blockIdx.x & 7;
    int n0 = nbk * 32;
    int t = threadIdx.x;
    int nl = t >> 3, j = t & 7;                        // 8 threads per n, same wave
    const float* base = L + bh * 65536 + n0 + nl;
    float mx = -3.4e38f;
    for (int m0 = 0; m0 < 256; m0 += 8)
        mx = fmaxf(mx, base[(m0 + j) * 256]);
    mx = fmaxf(mx, __shfl_xor(mx, 1));
    mx = fmaxf(mx, __shfl_xor(mx, 2));
    mx = fmaxf(mx, __shfl_xor(mx, 4));
    float sum = 0.f;
    for (int m0 = 0; m0 < 256; m0 += 8) {
        float v = base[(m0 + j) * 256];
        float e = __expf(v - mx);
        sum += e;
        Ps[nl * 264 + m0 + j] = e;                     // bank-conflict-free
    }
    sum += __shfl_xor(sum, 1);
    sum += __shfl_xor(sum, 2);
    sum += __shfl_xor(sum, 4);
    if (j == 0) inv_s[nl] = 1.0f / sum;
    __syncthreads();
    unsigned short* dst = pt + (bh * 256 + n0) * 256;  // transposed coalesced writeout
#pragma unroll 4
    for (int i = 0; i < 32; ++i)
        dst[i * 256 + t] = f2bf(Ps[i * 264 + t] * inv_s[i]);
}

// ---------------- 7. out[b,n,h*96+e] = sum_m Pt[n,m] * V[m,e] + f_a ----------------
__global__ __launch_bounds__(256) void k_attnv(const unsigned short* __restrict__ pt,
                                               const unsigned short* __restrict__ vt,
                                               const float* __restrict__ fa,
                                               float* __restrict__ out) {
    int w = threadIdx.x >> 6, lane = threadIdx.x & 63;
    int lrow = lane & 15, quad = lane >> 4;
    int tid = blockIdx.x * 4 + w;
    int bh = tid / 96, rem = tid - bh * 96;
    int nt = rem / 6, et = rem - nt * 6;
    int n0 = nt * 16, e0 = et * 16;
    int b_ = bh >> 3, h = bh & 7;
    f32x4 acc = {0.f, 0.f, 0.f, 0.f};
    const unsigned short* pa = pt + (bh * 256 + n0 + lrow) * 256 + quad * 8;  // A[n][m]
    const unsigned short* va = vt + (bh * 96 + e0 + lrow) * 256 + quad * 8;   // B[m][e] from [e][m]
#pragma unroll
    for (int mk = 0; mk < 256; mk += 32) {
        short8 a = *(const short8*)(pa + mk);
        short8 b = *(const short8*)(va + mk);
        acc = __builtin_amdgcn_mfma_f32_16x16x32_bf16(a, b, acc, 0, 0, 0);
    }
    int idx = (b_ * 256 + n0 + quad * 4) * 768 + h * 96 + e0 + lrow;
#pragma unroll
    for (int r = 0; r < 4; ++r)
        out[idx + r * 768] = acc[r] + fa[idx + r * 768];
}

extern "C" void kernel_launch(void* const* d_in, const int* in_sizes, int n_in,
                              void* d_out, int out_size, void* d_ws, size_t ws_size,
                              hipStream_t stream) {
    const float* fa  = (const float*)d_in[0];
    const float* pe  = (const float*)d_in[1];
    const float* wgw = (const float*)d_in[2];
    const float* wgb = (const float*)d_in[3];
    const float* wkw = (const float*)d_in[4];
    const float* wkb = (const float*)d_in[5];
    const float* wqw = (const float*)d_in[6];
    const float* wqb = (const float*)d_in[7];
    const float* wvw = (const float*)d_in[8];
    const float* wvb = (const float*)d_in[9];
    float* out = (float*)d_out;
    char* ws = (char*)d_ws;
    // workspace layout (41.3 MB total)
    unsigned short* abf = (unsigned short*)(ws);              // 2048*768 bf16   = 3,145,728 B
    unsigned short* wbf = (unsigned short*)(ws + 3145728);    // 2304*768 bf16   = 3,538,944 B
    unsigned short* kb  = (unsigned short*)(ws + 6684672);    // 64*256*96 bf16  = 3,145,728 B
    unsigned short* qb  = (unsigned short*)(ws + 9830400);    // 64*256*96 bf16  = 3,145,728 B
    unsigned short* vt  = (unsigned short*)(ws + 12976128);   // 64*96*256 bf16  = 3,145,728 B
    float*          L   = (float*)(ws + 16121856);            // 64*256*256 f32  = 16,777,216 B
    unsigned short* pt  = (unsigned short*)(ws + 32899072);   // 64*256*256 bf16 = 8,388,608 B

    k_cvt_a  <<<1536, 256, 0, stream>>>(fa, abf);
    k_cvt_w  <<< 288, 256, 0, stream>>>(wkw, wqw, wvw, wbf);
    k_proj   <<<1152, 256, 0, stream>>>(abf, wbf, wkb, wqb, wvb, kb, qb, vt);
    k_wg     <<<2048, 256, 0, stream>>>(pe, wgw, wgb, L);
    k_score  <<<4096, 256, 0, stream>>>(kb, qb, L);
    k_softmax<<< 512, 256, 0, stream>>>(L, pt);
    k_attnv  <<<1536, 256, 0, stream>>>(pt, vt, fa, out);
}

// Round 3
// 405.970 us; speedup vs baseline: 1.0334x; 1.0334x over previous
//
#include <hip/hip_runtime.h>

// Problem constants
#define DD   768      // appearance dim
#define NH   8        // heads
#define DKh  96       // key/geo dim

typedef __attribute__((ext_vector_type(8))) short short8;   // 8 bf16
typedef __attribute__((ext_vector_type(4))) float f32x4;

__device__ __forceinline__ unsigned short f2bf(float x) {
    union { float f; unsigned int u; } v; v.f = x;
    unsigned int r = v.u + 0x7FFFu + ((v.u >> 16) & 1u);   // RNE
    return (unsigned short)(r >> 16);
}

// ---------------- 1. f_a fp32 -> bf16 ----------------
__global__ __launch_bounds__(256) void k_cvt_a(const float* __restrict__ fa,
                                               unsigned short* __restrict__ abf) {
    int idx = blockIdx.x * 256 + threadIdx.x;          // 393216 float4 exactly
    float4 v = ((const float4*)fa)[idx];
    ushort4 o;
    o.x = f2bf(v.x); o.y = f2bf(v.y); o.z = f2bf(v.z); o.w = f2bf(v.w);
    ((ushort4*)abf)[idx] = o;
}

// ---------------- 2. W[K|Q|V] -> bf16, transposed to [col][d] ----------------
__global__ __launch_bounds__(256) void k_cvt_w(const float* __restrict__ wk,
                                               const float* __restrict__ wq,
                                               const float* __restrict__ wv,
                                               unsigned short* __restrict__ wbf) {
    __shared__ float ls[64 * 97];                      // pad 97: conflict-free
    int pid = blockIdx.x / 12;                         // 0..23 = (p,h)
    int db  = blockIdx.x % 12;                         // d-block of 64
    int p = pid >> 3, h = pid & 7;
    const float* src = (p == 0 ? wk : p == 1 ? wq : wv) + h * DD * DKh + db * 64 * DKh;
    int t = threadIdx.x;
#pragma unroll
    for (int i = 0; i < 24; ++i) {                     // 64 rows x 96, coalesced
        int f = t + 256 * i;
        int dl = f / 96, e = f - dl * 96;
        ls[dl * 97 + e] = src[f];
    }
    __syncthreads();
    unsigned short* dst = wbf + (p * 768 + h * 96) * DD + db * 64;
#pragma unroll
    for (int i = 0; i < 24; ++i) {
        int f = t + 256 * i;
        int e = f >> 6, dl = f & 63;
        dst[e * DD + dl] = f2bf(ls[dl * 97 + e]);
    }
}

// ---------------- 3. projections: C[2048x2304] = A x W, MFMA bf16 ----------------
// Block = 64 rows x 64 cols (waves take distinct 16-row strips; share B range via L1).
__global__ __launch_bounds__(256) void k_proj(const unsigned short* __restrict__ abf,
                                              const unsigned short* __restrict__ wbf,
                                              const float* __restrict__ wkb,
                                              const float* __restrict__ wqb,
                                              const float* __restrict__ wvb,
                                              unsigned short* __restrict__ kb,
                                              unsigned short* __restrict__ qb,
                                              unsigned short* __restrict__ vt) {
    int w = threadIdx.x >> 6, lane = threadIdx.x & 63;
    int lrow = lane & 15, quad = lane >> 4;
    int rt = blockIdx.x / 36, cg = blockIdx.x % 36;    // 32 row-tiles x 36 col-tiles
    int r0 = rt * 64 + w * 16;                         // wave: 16 rows x 64 cols
    int c0 = cg * 64;
    f32x4 z = {0.f, 0.f, 0.f, 0.f};
    f32x4 acc[4] = {z, z, z, z};
    for (int kk = 0; kk < DD; kk += 32) {
        short8 a = *(const short8*)(abf + (r0 + lrow) * DD + kk + quad * 8);
#pragma unroll
        for (int tt = 0; tt < 4; ++tt) {
            short8 b = *(const short8*)(wbf + (c0 + tt * 16 + lrow) * DD + kk + quad * 8);
            acc[tt] = __builtin_amdgcn_mfma_f32_16x16x32_bf16(a, b, acc[tt], 0, 0, 0);
        }
    }
    int rbase = r0 + quad * 4;
    int b_ = rbase >> 8, mbase = rbase & 255;
#pragma unroll
    for (int tt = 0; tt < 4; ++tt) {
        int cc = c0 + tt * 16 + lrow;
        int p = cc / 768, rm = cc - p * 768;
        int h = rm / 96,  e = rm - h * 96;
        float bias = (p == 0 ? wkb : p == 1 ? wqb : wvb)[h * 96 + e];
        if (p == 2) {                                  // V transposed: [e][m], m packed x4
            ushort4 v4;
            v4.x = f2bf(acc[tt][0] + bias);
            v4.y = f2bf(acc[tt][1] + bias);
            v4.z = f2bf(acc[tt][2] + bias);
            v4.w = f2bf(acc[tt][3] + bias);
            *(ushort4*)(vt + ((b_ * 8 + h) * 96 + e) * 256 + mbase) = v4;
        } else {
            float sc = (p == 1) ? 0.10206207261596577f : 1.0f;   // fold 1/sqrt(96) into Q
            unsigned short* dst = (p == 0 ? kb : qb) + ((b_ * 8 + h) * 256 + mbase) * 96 + e;
#pragma unroll
            for (int r = 0; r < 4; ++r)
                dst[r * 96] = f2bf((acc[tt][r] + bias) * sc);
        }
    }
}

// ---------------- 4. FUSED geometric bias + scores -> L ----------------
// Block = (b, 16m x 16n). Stage pe tile (256 rows x 96) coalesced -> bf16 LDS.
// Phase A: wg = pe_tile x WG^T via MFMA (B cols = heads, padded to 16);
//          log(max(.,1e-6)) -> stot LDS (layout bridge).
// Phase B: scores K.Q^T per head via MFMA (frags from L2-resident kb/qb),
//          add stot, write L[b,h,m,n] once (no RMW).
__global__ __launch_bounds__(256) void k_wgs(const float* __restrict__ pe,
                                             const float* __restrict__ wgw,
                                             const float* __restrict__ wgb,
                                             const unsigned short* __restrict__ kb,
                                             const unsigned short* __restrict__ qb,
                                             float* __restrict__ L) {
    __shared__ unsigned short peb[256 * 96];           // 48 KB bf16 pe tile
    __shared__ unsigned short wgl[16 * 96];            // 3 KB  WG^T [col][k], cols 8..15 = 0
    __shared__ float stot[8 * 256];                    // 8 KB  [h][mi*16+ni]
    int bi = blockIdx.x;
    int b = bi >> 8, mt = (bi >> 4) & 15, nt = bi & 15;
    int m0 = mt * 16, n0 = nt * 16;
    int t = threadIdx.x;
    // stage WG^T (bf16)
#pragma unroll
    for (int i = 0; i < 6; ++i) {
        int f = t + 256 * i;                           // 1536 = 16 cols x 96
        int c = f / 96, k = f - c * 96;
        wgl[f] = (c < 8) ? f2bf(wgw[c * 96 + k]) : (unsigned short)0;
    }
    // stage pe tile: 16 chunks (one per mi) of 16 n-rows x 96 contiguous floats
    const float* peg = pe + ((size_t)(b * 256 + m0) * 256 + n0) * 96;
#pragma unroll
    for (int i = 0; i < 24; ++i) {
        int f = t + 256 * i;                           // float4 idx, 6144 total
        int mi = f / 384, rem = f - mi * 384;          // 384 float4 per chunk
        float4 v = *(const float4*)(peg + (size_t)mi * 24576 + rem * 4);
        ushort4 o;
        o.x = f2bf(v.x); o.y = f2bf(v.y); o.z = f2bf(v.z); o.w = f2bf(v.w);
        *(ushort4*)(peb + mi * 1536 + rem * 4) = o;
    }
    __syncthreads();
    int w = t >> 6, lane = t & 63, lrow = lane & 15, quad = lane >> 4;
    // ---- Phase A: wg MFMA. wave w -> row-tiles w*4 .. w*4+3 (16 pe-rows each)
    short8 bf[3];
#pragma unroll
    for (int ks = 0; ks < 3; ++ks)
        bf[ks] = *(const short8*)(wgl + lrow * 96 + ks * 32 + quad * 8);
    float gbias = wgb[lrow & 7];
#pragma unroll
    for (int rt4 = 0; rt4 < 4; ++rt4) {
        int rt = w * 4 + rt4;
        f32x4 acc = {0.f, 0.f, 0.f, 0.f};
#pragma unroll
        for (int ks = 0; ks < 3; ++ks) {
            short8 a = *(const short8*)(peb + (rt * 16 + lrow) * 96 + ks * 32 + quad * 8);
            acc = __builtin_amdgcn_mfma_f32_16x16x32_bf16(a, bf[ks], acc, 0, 0, 0);
        }
        if (lrow < 8) {                                // col = h = lrow; row = rt*16+quad*4+r
#pragma unroll
            for (int r = 0; r < 4; ++r)
                stot[lrow * 256 + rt * 16 + quad * 4 + r] =
                    __logf(fmaxf(acc[r] + gbias, 1e-6f));
        }
    }
    __syncthreads();
    // ---- Phase B: scores, heads h = 2w, 2w+1
#pragma unroll
    for (int hh = 0; hh < 2; ++hh) {
        int h = w * 2 + hh;
        const unsigned short* ka = kb + ((size_t)((b * 8 + h) * 256) + m0 + lrow) * 96 + quad * 8;
        const unsigned short* qa = qb + ((size_t)((b * 8 + h) * 256) + n0 + lrow) * 96 + quad * 8;
        f32x4 acc = {0.f, 0.f, 0.f, 0.f};
#pragma unroll
        for (int ks = 0; ks < 3; ++ks) {
            short8 a  = *(const short8*)(ka + ks * 32);
            short8 bq = *(const short8*)(qa + ks * 32);
            acc = __builtin_amdgcn_mfma_f32_16x16x32_bf16(a, bq, acc, 0, 0, 0);
        }
        float* lp = L + ((size_t)((b * 8 + h) * 256) + m0 + quad * 4) * 256 + n0 + lrow;
#pragma unroll
        for (int r = 0; r < 4; ++r)                    // D[m=quad*4+r][n=lrow]
            lp[r * 256] = acc[r] + stot[h * 256 + (quad * 4 + r) * 16 + lrow];
    }
}

// ---------------- 6. softmax over m (per b,h,n) -> Pt[b,h,n,m] bf16, normalized ----------------
__global__ __launch_bounds__(256) void k_softmax(const float* __restrict__ L,
                                                 unsigned short* __restrict__ pt) {
    __shared__ float Ps[32 * 264];                     // 32 n-rows x 256 m, pad 264
    __shared__ float inv_s[32];
    int bh = blockIdx.x >> 3, nbk = blockIdx.x & 7;
    int n0 = nbk * 32;
    int t = threadIdx.x;
    int nl = t >> 3, j = t & 7;                        // 8 threads per n, same wave
    const float* base = L + bh * 65536 + n0 + nl;
    float mx = -3.4e38f;
    for (int m0 = 0; m0 < 256; m0 += 8)
        mx = fmaxf(mx, base[(m0 + j) * 256]);
    mx = fmaxf(mx, __shfl_xor(mx, 1));
    mx = fmaxf(mx, __shfl_xor(mx, 2));
    mx = fmaxf(mx, __shfl_xor(mx, 4));
    float sum = 0.f;
    for (int m0 = 0; m0 < 256; m0 += 8) {
        float v = base[(m0 + j) * 256];
        float e = __expf(v - mx);
        sum += e;
        Ps[nl * 264 + m0 + j] = e;                     // bank-conflict-free
    }
    sum += __shfl_xor(sum, 1);
    sum += __shfl_xor(sum, 2);
    sum += __shfl_xor(sum, 4);
    if (j == 0) inv_s[nl] = 1.0f / sum;
    __syncthreads();
    unsigned short* dst = pt + (bh * 256 + n0) * 256;  // transposed coalesced writeout
#pragma unroll 4
    for (int i = 0; i < 32; ++i)
        dst[i * 256 + t] = f2bf(Ps[i * 264 + t] * inv_s[i]);
}

// ---------------- 7. out[b,n,h*96+e] = sum_m Pt[n,m] * V[m,e] + f_a ----------------
__global__ __launch_bounds__(256) void k_attnv(const unsigned short* __restrict__ pt,
                                               const unsigned short* __restrict__ vt,
                                               const float* __restrict__ fa,
                                               float* __restrict__ out) {
    int w = threadIdx.x >> 6, lane = threadIdx.x & 63;
    int lrow = lane & 15, quad = lane >> 4;
    int tid = blockIdx.x * 4 + w;
    int bh = tid / 96, rem = tid - bh * 96;
    int nt = rem / 6, et = rem - nt * 6;
    int n0 = nt * 16, e0 = et * 16;
    int b_ = bh >> 3, h = bh & 7;
    f32x4 acc = {0.f, 0.f, 0.f, 0.f};
    const unsigned short* pa = pt + (bh * 256 + n0 + lrow) * 256 + quad * 8;  // A[n][m]
    const unsigned short* va = vt + (bh * 96 + e0 + lrow) * 256 + quad * 8;   // B[m][e] from [e][m]
#pragma unroll
    for (int mk = 0; mk < 256; mk += 32) {
        short8 a = *(const short8*)(pa + mk);
        short8 b = *(const short8*)(va + mk);
        acc = __builtin_amdgcn_mfma_f32_16x16x32_bf16(a, b, acc, 0, 0, 0);
    }
    int idx = (b_ * 256 + n0 + quad * 4) * 768 + h * 96 + e0 + lrow;
#pragma unroll
    for (int r = 0; r < 4; ++r)
        out[idx + r * 768] = acc[r] + fa[idx + r * 768];
}

extern "C" void kernel_launch(void* const* d_in, const int* in_sizes, int n_in,
                              void* d_out, int out_size, void* d_ws, size_t ws_size,
                              hipStream_t stream) {
    const float* fa  = (const float*)d_in[0];
    const float* pe  = (const float*)d_in[1];
    const float* wgw = (const float*)d_in[2];
    const float* wgb = (const float*)d_in[3];
    const float* wkw = (const float*)d_in[4];
    const float* wkb = (const float*)d_in[5];
    const float* wqw = (const float*)d_in[6];
    const float* wqb = (const float*)d_in[7];
    const float* wvw = (const float*)d_in[8];
    const float* wvb = (const float*)d_in[9];
    float* out = (float*)d_out;
    char* ws = (char*)d_ws;
    unsigned short* abf = (unsigned short*)(ws);              // 2048*768 bf16
    unsigned short* wbf = (unsigned short*)(ws + 3145728);    // 2304*768 bf16
    unsigned short* kb  = (unsigned short*)(ws + 6684672);    // [b,h,m,e] bf16
    unsigned short* qb  = (unsigned short*)(ws + 9830400);    // [b,h,n,e] bf16 (scaled)
    unsigned short* vt  = (unsigned short*)(ws + 12976128);   // [b,h,e,m] bf16
    float*          L   = (float*)(ws + 16121856);            // [b,h,m,n] f32
    unsigned short* pt  = (unsigned short*)(ws + 32899072);   // [b,h,n,m] bf16

    k_cvt_a  <<<1536, 256, 0, stream>>>(fa, abf);
    k_cvt_w  <<< 288, 256, 0, stream>>>(wkw, wqw, wvw, wbf);
    k_proj   <<<1152, 256, 0, stream>>>(abf, wbf, wkb, wqb, wvb, kb, qb, vt);
    k_wgs    <<<2048, 256, 0, stream>>>(pe, wgw, wgb, kb, qb, L);
    k_softmax<<< 512, 256, 0, stream>>>(L, pt);
    k_attnv  <<<1536, 256, 0, stream>>>(pt, vt, fa, out);
}